// Round 7
// baseline (98.552 us; speedup 1.0000x reference)
//
#include <hip/hip_runtime.h>
#include <math.h>

#define HH 480
#define WW 640
#define NL 100
#define NREF 20
#define RPB 2                 /* rows per block */
#define NB (HH / RPB)         /* 240 blocks */

// ws layout: float partial[col][block], col = t*4+q (80 cols), col stride NB
// floats (960 B, 16B-aligned) -> words [0, 19200). int done counter at word
// 19200 (zeroed each call by a 4-byte hipMemsetAsync). No atomics on data.

__global__ __launch_bounds__(256) void plane_fused_kernel(
    const float* __restrict__ depth, const int* __restrict__ valid,
    const float* __restrict__ line_pred, const float* __restrict__ line_score,
    float* __restrict__ w, float* __restrict__ out) {
    __shared__ float ds[(RPB + 2) * WW];   // rows base-1 .. base+RPB (zero-filled OOB)
    __shared__ int vsh[RPB * WW];
    __shared__ float s_sc[NL];
    __shared__ float s_vert[NREF][6];      // vx,vy x 3 per rank
    __shared__ float s_ae[RPB][NREF * 3];  // per-row edge constant
    __shared__ float s_ey[NREF * 3];
    __shared__ int s_last;

    const int tid = threadIdx.x;
    const int base = blockIdx.x * RPB;

    if (tid < NL) s_sc[tid] = ((const float2*)line_score)[tid].x;

    // stage depth: (RPB+2) rows x 160 float4
    for (int idx = tid; idx < (RPB + 2) * (WW / 4); idx += 256) {
        const int lr = idx / (WW / 4);
        const int c4 = idx - lr * (WW / 4);
        const int g = base - 1 + lr;
        float4 v = make_float4(0.f, 0.f, 0.f, 0.f);
        if ((unsigned)g < (unsigned)HH) v = ((const float4*)depth)[g * (WW / 4) + c4];
        ((float4*)ds)[idx] = v;
    }
    // stage valid rows
    for (int idx = tid; idx < RPB * (WW / 4); idx += 256)
        ((int4*)vsh)[idx] = ((const int4*)valid)[base * (WW / 4) + idx];
    __syncthreads();

    // stable rank == jax.lax.top_k order (desc, ties -> lower idx); permutation
    if (tid < NL) {
        const float s0 = s_sc[tid];
        int rank = 0;
        for (int j = 0; j < NL; j++) {
            const float sj = s_sc[j];
            rank += ((sj > s0) || (sj == s0 && j < tid)) ? 1 : 0;
        }
        if (rank < NREF) {
            const float2 c01 = ((const float2*)line_pred)[3 * tid];
            const float2 c23 = ((const float2*)line_pred)[3 * tid + 1];
            const float2 c45 = ((const float2*)line_pred)[3 * tid + 2];
            // round half-even == jnp.round; clip to image
            s_vert[rank][0] = fminf(fmaxf(rintf(c01.x * (float)WW), 0.f), (float)(WW - 1));
            s_vert[rank][1] = fminf(fmaxf(rintf(c01.y * (float)HH), 0.f), (float)(HH - 1));
            s_vert[rank][2] = fminf(fmaxf(rintf(c23.x * (float)WW), 0.f), (float)(WW - 1));
            s_vert[rank][3] = fminf(fmaxf(rintf(c23.y * (float)HH), 0.f), (float)(HH - 1));
            s_vert[rank][4] = fminf(fmaxf(rintf(c45.x * (float)WW), 0.f), (float)(WW - 1));
            s_vert[rank][5] = fminf(fmaxf(rintf(c45.y * (float)HH), 0.f), (float)(HH - 1));
        }
    }
    __syncthreads();

    // per-row edge constants: d_e(px) = ae_e - ey_e*px (exact: integer fp32
    // operands, |terms| < 2^22 -> sign test bitwise-identical to reference)
    if (tid < NREF * 3) {
        const int t = tid / 3, e = tid - 3 * t, n = (e + 1) % 3;
        const float vx = s_vert[t][2 * e], vy = s_vert[t][2 * e + 1];
        const float ex = s_vert[t][2 * n] - vx, eyv = s_vert[t][2 * n + 1] - vy;
        s_ey[tid] = eyv;
        #pragma unroll
        for (int rr = 0; rr < RPB; rr++)
            s_ae[rr][tid] = fmaf(ex, (float)(base + rr) - vy, eyv * vx);
    }
    __syncthreads();

    const int wid = tid >> 6, lane = tid & 63;
    float eyr[5][3];
    #pragma unroll
    for (int i = 0; i < 5; i++)
        #pragma unroll
        for (int e = 0; e < 3; e++)
            eyr[i][e] = s_ey[(wid * 5 + i) * 3 + e];

    float acc[5][4];
    #pragma unroll
    for (int i = 0; i < 5; i++)
        #pragma unroll
        for (int q = 0; q < 4; q++) acc[i][q] = 0.f;

    #pragma unroll
    for (int rr = 0; rr < RPB; rr++) {
        float ae[5][3];
        #pragma unroll
        for (int i = 0; i < 5; i++)
            #pragma unroll
            for (int e = 0; e < 3; e++)
                ae[i][e] = s_ae[rr][(wid * 5 + i) * 3 + e];
        const float* rm = ds + rr * WW;
        const float* rc = ds + (rr + 1) * WW;
        const float* rp = ds + (rr + 2) * WW;
        const int* vrow = vsh + rr * WW;
        #pragma unroll
        for (int j = 0; j < 10; j++) {
            const int x = j * 64 + lane;
            const float px = (float)x;
            const float fl = (x > 0) ? 1.f : 0.f;
            const float fr = (x < WW - 1) ? 1.f : 0.f;
            const int xm = x - (x > 0), xp = x + (x < WW - 1);
            const float a00 = rm[xm] * fl, a01 = rm[x], a02 = rm[xp] * fr;
            const float a10 = rc[xm] * fl,               a12 = rc[xp] * fr;
            const float a20 = rp[xm] * fl, a21 = rp[x], a22 = rp[xp] * fr;
            // XLA conv = cross-correlation, zero pad
            const float gx = (a00 - a02) + 2.f * (a10 - a12) + (a20 - a22);
            const float gy = (a00 + 2.f * a01 + a02) - (a20 + 2.f * a21 + a22);
            const float nx = -gx, ny = -gy;
            const float s2 = nx * nx + ny * ny;
            const bool vm = (vrow[x] != 0);
            #pragma unroll
            for (int i = 0; i < 5; i++) {
                const float d0 = fmaf(-eyr[i][0], px, ae[i][0]);
                const float d1 = fmaf(-eyr[i][1], px, ae[i][1]);
                const float d2 = fmaf(-eyr[i][2], px, ae[i][2]);
                const float dmin = fminf(fminf(d0, d1), d2);
                const float dmax = fmaxf(fmaxf(d0, d1), d2);
                const bool m = ((dmin >= 0.f) | (dmax <= 0.f)) & vm;
                const float mf = m ? 1.f : 0.f;
                acc[i][0] += mf;
                acc[i][1] = fmaf(mf, nx, acc[i][1]);
                acc[i][2] = fmaf(mf, ny, acc[i][2]);
                acc[i][3] = fmaf(mf, s2, acc[i][3]);
            }
        }
    }

    // wave-level reduction; waves own disjoint triangles -> no cross-wave step
    #pragma unroll
    for (int off = 32; off > 0; off >>= 1)
        #pragma unroll
        for (int i = 0; i < 5; i++)
            #pragma unroll
            for (int q = 0; q < 4; q++)
                acc[i][q] += __shfl_down(acc[i][q], off);
    if (lane == 0) {
        // plain stores, zero contention: col = (wid*5+i)*4+q, row = blockIdx.x
        #pragma unroll
        for (int i = 0; i < 5; i++)
            #pragma unroll
            for (int q = 0; q < 4; q++)
                w[((wid * 5 + i) * 4 + q) * NB + blockIdx.x] = acc[i][q];
    }

    // ---- split-K completion: release fence -> done counter -> last block ----
    __threadfence(); // make this block's partial stores device-visible
    if (tid == 0) {
        const int done = atomicAdd((int*)w + NREF * 4 * NB, 1);
        s_last = (done == NB - 1) ? 1 : 0;
    }
    __syncthreads();
    if (!s_last) return;

    __threadfence(); // acquire: refresh caches before reading others' partials

    // top_num = min(#(softmax prob0 > 0.6), 20); include-flag = (rank < top_num)
    __shared__ int s_cnt[4];
    __shared__ float s_col[NREF * 4];
    int flag = 0;
    if (tid < NL) {
        const float2 sc = ((const float2*)line_score)[tid];
        const float p0 = 1.0f / (1.0f + expf(sc.y - sc.x));
        flag = (p0 > 0.6f) ? 1 : 0;
    }
    const unsigned long long b = __ballot(flag);
    if (lane == 0) s_cnt[wid] = __popcll(b);

    // column sums: 80 threads, each 60 contiguous float4 loads (L2-hot)
    if (tid < NREF * 4) {
        const float4* col = (const float4*)(w + tid * NB);
        float4 s4 = make_float4(0.f, 0.f, 0.f, 0.f);
        #pragma unroll 4
        for (int p = 0; p < NB / 4; p++) {
            const float4 v = col[p];
            s4.x += v.x; s4.y += v.y; s4.z += v.z; s4.w += v.w;
        }
        s_col[tid] = (s4.x + s4.y) + (s4.z + s4.w);
    }
    __syncthreads();

    const int topnum = min(s_cnt[0] + s_cnt[1] + s_cnt[2] + s_cnt[3], NREF);
    float val = 0.f, inc = 0.f;
    if (tid < NREF) {
        const float c  = s_col[tid * 4 + 0];
        const float sx = s_col[tid * 4 + 1];
        const float sy = s_col[tid * 4 + 2];
        const float sq = s_col[tid * 4 + 3];
        const float safe = fmaxf(c, 1.f);
        const float mx = sx / safe, my = sy / safe;
        // (var_x+var_y) expanded; exact 0 when c==0
        const float var = (sq - 2.f * mx * sx - 2.f * my * sy
                           + c * (mx * mx + my * my)) / safe;
        inc = ((c >= 100.f) && (tid < topnum)) ? 1.f : 0.f;
        val = inc * var;
    }
    if (tid < 64) { // lanes 20..63 carry zeros
        #pragma unroll
        for (int off = 32; off > 0; off >>= 1) {
            val += __shfl_down(val, off);
            inc += __shfl_down(inc, off);
        }
        if (tid == 0) out[0] = val / fmaxf(inc, 1.f);
    }
}

extern "C" void kernel_launch(void* const* d_in, const int* in_sizes, int n_in,
                              void* d_out, int out_size, void* d_ws, size_t ws_size,
                              hipStream_t stream) {
    const float* depth_pred = (const float*)d_in[0];
    // d_in[1] = depth_gt (unused by reference)
    const float* line_pred  = (const float*)d_in[2];
    const float* line_score = (const float*)d_in[3];
    const int*   valid_mask = (const int*)d_in[4];
    float* out = (float*)d_out;
    float* w = (float*)d_ws;

    // zero ONLY the 4-byte done counter (ws is re-poisoned to 0xAA each call)
    hipMemsetAsync((char*)d_ws + NREF * 4 * NB * sizeof(float), 0, 4, stream);
    plane_fused_kernel<<<NB, 256, 0, stream>>>(depth_pred, valid_mask,
                                               line_pred, line_score, w, out);
}

// Round 8
// 82.151 us; speedup vs baseline: 1.1996x; 1.1996x over previous
//
#include <hip/hip_runtime.h>
#include <math.h>

#define HH 480
#define WW 640
#define NL 100
#define NREF 20
#define NB HH                 /* one block per row: 480 blocks */

// ws layout: PART only. partial[col][block], col = t*4+q (80 cols),
// col stride NB floats (1920 B, 16B-aligned), ~153.6 KB. No zeroing needed:
// every entry is plain-stored by its owning block. NO atomics, NO fences —
// the kernel boundary (stream order) provides cross-XCD coherence for free;
// R7 showed explicit __threadfence() costs ~50 µs in L2 writeback storms.

// One block per image row. Block derives its own triangle set from
// line_score/line_pred in LDS (no setup kernel). Each wave handles 5
// triangles over all 640 px (640 = 10*64: no boundary divergence).
// Gradient computed once per wave.
__global__ __launch_bounds__(256) void plane_main_kernel(
    const float* __restrict__ depth, const int* __restrict__ valid,
    const float* __restrict__ line_pred, const float* __restrict__ line_score,
    float* __restrict__ w) {
    __shared__ float ds[3 * WW];        // rows r-1, r, r+1 (zero-filled OOB)
    __shared__ int vsh[WW];
    __shared__ float s_sc[NL];
    __shared__ float s_vert[NREF][6];   // vx,vy x 3 per rank
    __shared__ float s_ae[NREF * 3];    // per-row edge constant
    __shared__ float s_ey[NREF * 3];

    const int tid = threadIdx.x;
    const int r = blockIdx.x;
    const float py = (float)r;

    if (tid < NL) s_sc[tid] = ((const float2*)line_score)[tid].x;

    // stage depth: 3 rows x 160 float4
    for (int idx = tid; idx < 3 * (WW / 4); idx += 256) {
        const int lr = idx / (WW / 4);
        const int c4 = idx - lr * (WW / 4);
        const int g = r - 1 + lr;
        float4 v = make_float4(0.f, 0.f, 0.f, 0.f);
        if ((unsigned)g < (unsigned)HH) v = ((const float4*)depth)[g * (WW / 4) + c4];
        ((float4*)ds)[idx] = v;
    }
    // stage valid row
    for (int idx = tid; idx < WW / 4; idx += 256)
        ((int4*)vsh)[idx] = ((const int4*)valid)[r * (WW / 4) + idx];
    __syncthreads();

    // stable rank == jax.lax.top_k order (desc, ties -> lower idx); permutation
    if (tid < NL) {
        const float s0 = s_sc[tid];
        int rank = 0;
        for (int j = 0; j < NL; j++) {
            const float sj = s_sc[j];
            rank += ((sj > s0) || (sj == s0 && j < tid)) ? 1 : 0;
        }
        if (rank < NREF) {
            const float2 c01 = ((const float2*)line_pred)[3 * tid];
            const float2 c23 = ((const float2*)line_pred)[3 * tid + 1];
            const float2 c45 = ((const float2*)line_pred)[3 * tid + 2];
            // round half-even == jnp.round; clip to image
            s_vert[rank][0] = fminf(fmaxf(rintf(c01.x * (float)WW), 0.f), (float)(WW - 1));
            s_vert[rank][1] = fminf(fmaxf(rintf(c01.y * (float)HH), 0.f), (float)(HH - 1));
            s_vert[rank][2] = fminf(fmaxf(rintf(c23.x * (float)WW), 0.f), (float)(WW - 1));
            s_vert[rank][3] = fminf(fmaxf(rintf(c23.y * (float)HH), 0.f), (float)(HH - 1));
            s_vert[rank][4] = fminf(fmaxf(rintf(c45.x * (float)WW), 0.f), (float)(WW - 1));
            s_vert[rank][5] = fminf(fmaxf(rintf(c45.y * (float)HH), 0.f), (float)(HH - 1));
        }
    }
    __syncthreads();

    // per-row edge constants: d_e(px) = ae_e - ey_e*px (exact: integer fp32
    // operands, |terms| < 2^22 -> sign test bitwise-identical to reference)
    if (tid < NREF * 3) {
        const int t = tid / 3, e = tid - 3 * t, n = (e + 1) % 3;
        const float vx = s_vert[t][2 * e], vy = s_vert[t][2 * e + 1];
        const float ex = s_vert[t][2 * n] - vx, eyv = s_vert[t][2 * n + 1] - vy;
        s_ey[tid] = eyv;
        s_ae[tid] = fmaf(ex, py - vy, eyv * vx);
    }
    __syncthreads();

    const int wid = tid >> 6, lane = tid & 63;
    float eyr[5][3], ae[5][3];
    #pragma unroll
    for (int i = 0; i < 5; i++)
        #pragma unroll
        for (int e = 0; e < 3; e++) {
            eyr[i][e] = s_ey[(wid * 5 + i) * 3 + e];
            ae[i][e]  = s_ae[(wid * 5 + i) * 3 + e];
        }

    float acc[5][4];
    #pragma unroll
    for (int i = 0; i < 5; i++)
        #pragma unroll
        for (int q = 0; q < 4; q++) acc[i][q] = 0.f;

    #pragma unroll
    for (int j = 0; j < 10; j++) {
        const int x = j * 64 + lane;
        const float px = (float)x;
        const float fl = (x > 0) ? 1.f : 0.f;
        const float fr = (x < WW - 1) ? 1.f : 0.f;
        const int xm = x - (x > 0), xp = x + (x < WW - 1);
        const float a00 = ds[xm] * fl,          a01 = ds[x],          a02 = ds[xp] * fr;
        const float a10 = ds[WW + xm] * fl,                           a12 = ds[WW + xp] * fr;
        const float a20 = ds[2 * WW + xm] * fl, a21 = ds[2 * WW + x], a22 = ds[2 * WW + xp] * fr;
        // XLA conv = cross-correlation, zero pad
        const float gx = (a00 - a02) + 2.f * (a10 - a12) + (a20 - a22);
        const float gy = (a00 + 2.f * a01 + a02) - (a20 + 2.f * a21 + a22);
        const float nx = -gx, ny = -gy;
        const float s2 = nx * nx + ny * ny;
        const bool vm = (vsh[x] != 0);
        #pragma unroll
        for (int i = 0; i < 5; i++) {
            const float d0 = fmaf(-eyr[i][0], px, ae[i][0]);
            const float d1 = fmaf(-eyr[i][1], px, ae[i][1]);
            const float d2 = fmaf(-eyr[i][2], px, ae[i][2]);
            const float dmin = fminf(fminf(d0, d1), d2);
            const float dmax = fmaxf(fmaxf(d0, d1), d2);
            const bool m = ((dmin >= 0.f) | (dmax <= 0.f)) & vm;
            const float mf = m ? 1.f : 0.f;
            acc[i][0] += mf;
            acc[i][1] = fmaf(mf, nx, acc[i][1]);
            acc[i][2] = fmaf(mf, ny, acc[i][2]);
            acc[i][3] = fmaf(mf, s2, acc[i][3]);
        }
    }

    // wave-level reduction; waves own disjoint triangles -> no cross-wave step
    #pragma unroll
    for (int off = 32; off > 0; off >>= 1)
        #pragma unroll
        for (int i = 0; i < 5; i++)
            #pragma unroll
            for (int q = 0; q < 4; q++)
                acc[i][q] += __shfl_down(acc[i][q], off);
    if (lane == 0) {
        // plain stores, zero contention: col = (wid*5+i)*4+q, row = blockIdx.x
        #pragma unroll
        for (int i = 0; i < 5; i++)
            #pragma unroll
            for (int q = 0; q < 4; q++)
                w[((wid * 5 + i) * 4 + q) * NB + r] = acc[i][q];
    }
}

__global__ __launch_bounds__(128) void plane_finalize_kernel(
    const float* __restrict__ line_score, const float* __restrict__ w,
    float* __restrict__ out) {
    __shared__ float s_col[NREF * 4];
    __shared__ int s_cnt[2];
    const int tid = threadIdx.x; // 0..127
    const int lane = tid & 63, wid = tid >> 6;

    // top_num = min(#(softmax prob0 > 0.6), 20); include-flag = (rank < top_num)
    int flag = 0;
    if (tid < NL) {
        const float2 sc = ((const float2*)line_score)[tid];
        const float p0 = 1.0f / (1.0f + expf(sc.y - sc.x));
        flag = (p0 > 0.6f) ? 1 : 0;
    }
    const unsigned long long b = __ballot(flag);
    if (lane == 0) s_cnt[wid] = __popcll(b);

    // sum partial columns (NB=480 contiguous floats each, float4)
    if (tid < NREF * 4) {
        const float4* col = (const float4*)(w + tid * NB);
        float4 s4 = make_float4(0.f, 0.f, 0.f, 0.f);
        #pragma unroll 8
        for (int p = 0; p < NB / 4; p++) {
            const float4 v = col[p];
            s4.x += v.x; s4.y += v.y; s4.z += v.z; s4.w += v.w;
        }
        s_col[tid] = (s4.x + s4.y) + (s4.z + s4.w);
    }
    __syncthreads();

    const int topnum = min(s_cnt[0] + s_cnt[1], NREF);
    float val = 0.f, inc = 0.f;
    if (tid < NREF) {
        const float c  = s_col[tid * 4 + 0];
        const float sx = s_col[tid * 4 + 1];
        const float sy = s_col[tid * 4 + 2];
        const float sq = s_col[tid * 4 + 3];
        const float safe = fmaxf(c, 1.f);
        const float mx = sx / safe, my = sy / safe;
        // (var_x+var_y) expanded; exact 0 when c==0
        const float var = (sq - 2.f * mx * sx - 2.f * my * sy
                           + c * (mx * mx + my * my)) / safe;
        inc = ((c >= 100.f) && (tid < topnum)) ? 1.f : 0.f;
        val = inc * var;
    }
    if (tid < 64) { // lanes 20..63 carry zeros
        #pragma unroll
        for (int off = 32; off > 0; off >>= 1) {
            val += __shfl_down(val, off);
            inc += __shfl_down(inc, off);
        }
        if (tid == 0) out[0] = val / fmaxf(inc, 1.f);
    }
}

extern "C" void kernel_launch(void* const* d_in, const int* in_sizes, int n_in,
                              void* d_out, int out_size, void* d_ws, size_t ws_size,
                              hipStream_t stream) {
    const float* depth_pred = (const float*)d_in[0];
    // d_in[1] = depth_gt (unused by reference)
    const float* line_pred  = (const float*)d_in[2];
    const float* line_score = (const float*)d_in[3];
    const int*   valid_mask = (const int*)d_in[4];
    float* out = (float*)d_out;
    float* w = (float*)d_ws;

    plane_main_kernel<<<NB, 256, 0, stream>>>(depth_pred, valid_mask,
                                              line_pred, line_score, w);
    plane_finalize_kernel<<<1, 128, 0, stream>>>(line_score, w, out);
}

// Round 9
// 78.512 us; speedup vs baseline: 1.2552x; 1.0463x over previous
//
#include <hip/hip_runtime.h>
#include <math.h>

#define HH 480
#define WW 640
#define NL 100
#define NREF 20
#define RPB 2                 /* rows per block */
#define NB (HH / RPB)         /* 240 blocks */

// ws layout: PART only. partial[col][block], col = t*4+q (80 cols),
// col stride NB floats (960 B, 16B-aligned). ~76.8 KB. No zeroing needed:
// every entry is plain-stored by its owning block. NO atomics, NO fences —
// the kernel boundary (stream order) provides cross-XCD coherence for free;
// R7 showed explicit __threadfence() costs ~50 µs in L2 writeback storms.
// RPB=2 beats RPB=1 (R6 79.1 vs R8 82.2): half the halo staging, half the
// rank-loop instances, half the partial matrix.

__global__ __launch_bounds__(256) void plane_main_kernel(
    const float* __restrict__ depth, const int* __restrict__ valid,
    const float* __restrict__ line_pred, const float* __restrict__ line_score,
    float* __restrict__ w) {
    __shared__ float ds[(RPB + 2) * WW];   // rows base-1 .. base+RPB (zero-filled OOB)
    __shared__ int vsh[RPB * WW];
    __shared__ float s_sc[NL];
    __shared__ float s_vert[NREF][6];      // vx,vy x 3 per rank
    __shared__ float s_ae[RPB][NREF * 3];  // per-row edge constant
    __shared__ float s_ey[NREF * 3];

    const int tid = threadIdx.x;
    const int base = blockIdx.x * RPB;

    if (tid < NL) s_sc[tid] = ((const float2*)line_score)[tid].x;

    // stage depth: (RPB+2) rows x 160 float4
    for (int idx = tid; idx < (RPB + 2) * (WW / 4); idx += 256) {
        const int lr = idx / (WW / 4);
        const int c4 = idx - lr * (WW / 4);
        const int g = base - 1 + lr;
        float4 v = make_float4(0.f, 0.f, 0.f, 0.f);
        if ((unsigned)g < (unsigned)HH) v = ((const float4*)depth)[g * (WW / 4) + c4];
        ((float4*)ds)[idx] = v;
    }
    // stage valid rows
    for (int idx = tid; idx < RPB * (WW / 4); idx += 256)
        ((int4*)vsh)[idx] = ((const int4*)valid)[base * (WW / 4) + idx];
    __syncthreads();

    // stable rank == jax.lax.top_k order (desc, ties -> lower idx); permutation
    if (tid < NL) {
        const float s0 = s_sc[tid];
        int rank = 0;
        for (int j = 0; j < NL; j++) {
            const float sj = s_sc[j];
            rank += ((sj > s0) || (sj == s0 && j < tid)) ? 1 : 0;
        }
        if (rank < NREF) {
            const float2 c01 = ((const float2*)line_pred)[3 * tid];
            const float2 c23 = ((const float2*)line_pred)[3 * tid + 1];
            const float2 c45 = ((const float2*)line_pred)[3 * tid + 2];
            // round half-even == jnp.round; clip to image
            s_vert[rank][0] = fminf(fmaxf(rintf(c01.x * (float)WW), 0.f), (float)(WW - 1));
            s_vert[rank][1] = fminf(fmaxf(rintf(c01.y * (float)HH), 0.f), (float)(HH - 1));
            s_vert[rank][2] = fminf(fmaxf(rintf(c23.x * (float)WW), 0.f), (float)(WW - 1));
            s_vert[rank][3] = fminf(fmaxf(rintf(c23.y * (float)HH), 0.f), (float)(HH - 1));
            s_vert[rank][4] = fminf(fmaxf(rintf(c45.x * (float)WW), 0.f), (float)(WW - 1));
            s_vert[rank][5] = fminf(fmaxf(rintf(c45.y * (float)HH), 0.f), (float)(HH - 1));
        }
    }
    __syncthreads();

    // per-row edge constants: d_e(px) = ae_e - ey_e*px (exact: integer fp32
    // operands, |terms| < 2^22 -> sign test bitwise-identical to reference)
    if (tid < NREF * 3) {
        const int t = tid / 3, e = tid - 3 * t, n = (e + 1) % 3;
        const float vx = s_vert[t][2 * e], vy = s_vert[t][2 * e + 1];
        const float ex = s_vert[t][2 * n] - vx, eyv = s_vert[t][2 * n + 1] - vy;
        s_ey[tid] = eyv;
        #pragma unroll
        for (int rr = 0; rr < RPB; rr++)
            s_ae[rr][tid] = fmaf(ex, (float)(base + rr) - vy, eyv * vx);
    }
    __syncthreads();

    const int wid = tid >> 6, lane = tid & 63;
    float eyr[5][3];
    #pragma unroll
    for (int i = 0; i < 5; i++)
        #pragma unroll
        for (int e = 0; e < 3; e++)
            eyr[i][e] = s_ey[(wid * 5 + i) * 3 + e];

    float acc[5][4];
    #pragma unroll
    for (int i = 0; i < 5; i++)
        #pragma unroll
        for (int q = 0; q < 4; q++) acc[i][q] = 0.f;

    #pragma unroll
    for (int rr = 0; rr < RPB; rr++) {
        float ae[5][3];
        #pragma unroll
        for (int i = 0; i < 5; i++)
            #pragma unroll
            for (int e = 0; e < 3; e++)
                ae[i][e] = s_ae[rr][(wid * 5 + i) * 3 + e];
        const float* rm = ds + rr * WW;
        const float* rc = ds + (rr + 1) * WW;
        const float* rp = ds + (rr + 2) * WW;
        const int* vrow = vsh + rr * WW;
        #pragma unroll
        for (int j = 0; j < 10; j++) {
            const int x = j * 64 + lane;
            const float px = (float)x;
            const float fl = (x > 0) ? 1.f : 0.f;
            const float fr = (x < WW - 1) ? 1.f : 0.f;
            const int xm = x - (x > 0), xp = x + (x < WW - 1);
            const float a00 = rm[xm] * fl, a01 = rm[x], a02 = rm[xp] * fr;
            const float a10 = rc[xm] * fl,               a12 = rc[xp] * fr;
            const float a20 = rp[xm] * fl, a21 = rp[x], a22 = rp[xp] * fr;
            // XLA conv = cross-correlation, zero pad
            const float gx = (a00 - a02) + 2.f * (a10 - a12) + (a20 - a22);
            const float gy = (a00 + 2.f * a01 + a02) - (a20 + 2.f * a21 + a22);
            const float nx = -gx, ny = -gy;
            const float s2 = nx * nx + ny * ny;
            const bool vm = (vrow[x] != 0);
            #pragma unroll
            for (int i = 0; i < 5; i++) {
                const float d0 = fmaf(-eyr[i][0], px, ae[i][0]);
                const float d1 = fmaf(-eyr[i][1], px, ae[i][1]);
                const float d2 = fmaf(-eyr[i][2], px, ae[i][2]);
                const float dmin = fminf(fminf(d0, d1), d2);
                const float dmax = fmaxf(fmaxf(d0, d1), d2);
                const bool m = ((dmin >= 0.f) | (dmax <= 0.f)) & vm;
                const float mf = m ? 1.f : 0.f;
                acc[i][0] += mf;
                acc[i][1] = fmaf(mf, nx, acc[i][1]);
                acc[i][2] = fmaf(mf, ny, acc[i][2]);
                acc[i][3] = fmaf(mf, s2, acc[i][3]);
            }
        }
    }

    // wave-level reduction; waves own disjoint triangles -> no cross-wave step
    #pragma unroll
    for (int off = 32; off > 0; off >>= 1)
        #pragma unroll
        for (int i = 0; i < 5; i++)
            #pragma unroll
            for (int q = 0; q < 4; q++)
                acc[i][q] += __shfl_down(acc[i][q], off);
    if (lane == 0) {
        // plain stores, zero contention: col = (wid*5+i)*4+q, row = blockIdx.x
        #pragma unroll
        for (int i = 0; i < 5; i++)
            #pragma unroll
            for (int q = 0; q < 4; q++)
                w[((wid * 5 + i) * 4 + q) * NB + blockIdx.x] = acc[i][q];
    }
}

__global__ __launch_bounds__(128) void plane_finalize_kernel(
    const float* __restrict__ line_score, const float* __restrict__ w,
    float* __restrict__ out) {
    __shared__ float s_col[NREF * 4];
    __shared__ int s_cnt[2];
    const int tid = threadIdx.x; // 0..127
    const int lane = tid & 63, wid = tid >> 6;

    // top_num = min(#(softmax prob0 > 0.6), 20); include-flag = (rank < top_num)
    int flag = 0;
    if (tid < NL) {
        const float2 sc = ((const float2*)line_score)[tid];
        const float p0 = 1.0f / (1.0f + expf(sc.y - sc.x));
        flag = (p0 > 0.6f) ? 1 : 0;
    }
    const unsigned long long b = __ballot(flag);
    if (lane == 0) s_cnt[wid] = __popcll(b);

    // sum partial columns (NB contiguous floats each, float4)
    if (tid < NREF * 4) {
        const float4* col = (const float4*)(w + tid * NB);
        float4 s4 = make_float4(0.f, 0.f, 0.f, 0.f);
        #pragma unroll 4
        for (int p = 0; p < NB / 4; p++) {
            const float4 v = col[p];
            s4.x += v.x; s4.y += v.y; s4.z += v.z; s4.w += v.w;
        }
        s_col[tid] = (s4.x + s4.y) + (s4.z + s4.w);
    }
    __syncthreads();

    const int topnum = min(s_cnt[0] + s_cnt[1], NREF);
    float val = 0.f, inc = 0.f;
    if (tid < NREF) {
        const float c  = s_col[tid * 4 + 0];
        const float sx = s_col[tid * 4 + 1];
        const float sy = s_col[tid * 4 + 2];
        const float sq = s_col[tid * 4 + 3];
        const float safe = fmaxf(c, 1.f);
        const float mx = sx / safe, my = sy / safe;
        // (var_x+var_y) expanded; exact 0 when c==0
        const float var = (sq - 2.f * mx * sx - 2.f * my * sy
                           + c * (mx * mx + my * my)) / safe;
        inc = ((c >= 100.f) && (tid < topnum)) ? 1.f : 0.f;
        val = inc * var;
    }
    if (tid < 64) { // lanes 20..63 carry zeros
        #pragma unroll
        for (int off = 32; off > 0; off >>= 1) {
            val += __shfl_down(val, off);
            inc += __shfl_down(inc, off);
        }
        if (tid == 0) out[0] = val / fmaxf(inc, 1.f);
    }
}

extern "C" void kernel_launch(void* const* d_in, const int* in_sizes, int n_in,
                              void* d_out, int out_size, void* d_ws, size_t ws_size,
                              hipStream_t stream) {
    const float* depth_pred = (const float*)d_in[0];
    // d_in[1] = depth_gt (unused by reference)
    const float* line_pred  = (const float*)d_in[2];
    const float* line_score = (const float*)d_in[3];
    const int*   valid_mask = (const int*)d_in[4];
    float* out = (float*)d_out;
    float* w = (float*)d_ws;

    plane_main_kernel<<<NB, 256, 0, stream>>>(depth_pred, valid_mask,
                                              line_pred, line_score, w);
    plane_finalize_kernel<<<1, 128, 0, stream>>>(line_score, w, out);
}